// Round 2
// baseline (384.581 us; speedup 1.0000x reference)
//
#include <hip/hip_runtime.h>
#include <hip/hip_bf16.h>

// GroupFC: C[32768,1024] = A[32768,1024] @ W[1024,1024]^T + b[1024], fp32 in/out.
// R5: keep the fusion (A read once as fp32, no convert pass) but restore the
// all-global_load_lds DMA pipeline that made R3 fast:
//   - A is staged into LDS AS FP32 via global_load_lds (8x16B rounds/iter),
//     and converted to bf16 at FRAGMENT-LOAD time (32B LDS read + 8 cvt per
//     fragment) inside the MFMA phase, where the idle VALU (11% busy) and the
//     MFMA pipe co-schedule for free.  No reg-staged latch, no ds_write, no
//     second serial phase -> back to one vmcnt drain per K-iteration.
//   - W stays bf16 (2 MB pre-convert) on the existing global_load_lds path.
//   - XCD-aware bijective grid swizzle kept (it fixed FETCH 265->109 MB).
// LDS/block = 32KB (A fp32) + 16KB (B bf16) = 48KB -> 3 blocks/CU.

#define M_DIM 32768
#define N_DIM 1024
#define K_DIM 1024
#define BM 128
#define BN 128
#define BK 64

typedef __attribute__((ext_vector_type(8))) short bf16x8;
typedef __attribute__((ext_vector_type(16))) float f32x16;
typedef __attribute__((ext_vector_type(8))) unsigned short ushort8v;

typedef const __attribute__((address_space(1))) unsigned int* gptr_t;
typedef __attribute__((address_space(3))) unsigned int* lptr_t;

static __device__ __forceinline__ unsigned short f2bf(float x) {
    union { __hip_bfloat16 h; unsigned short u; } cv;
    cv.h = __float2bfloat16(x);  // RNE
    return cv.u;
}

static __device__ __forceinline__ bf16x8 cvt8(float4 lo, float4 hi) {
    bf16x8 r;
    r[0] = (short)f2bf(lo.x); r[1] = (short)f2bf(lo.y);
    r[2] = (short)f2bf(lo.z); r[3] = (short)f2bf(lo.w);
    r[4] = (short)f2bf(hi.x); r[5] = (short)f2bf(hi.y);
    r[6] = (short)f2bf(hi.z); r[7] = (short)f2bf(hi.w);
    return r;
}

// ---------------- pass 1 (W only, 2 MB): fp32 -> bf16 ----------------
__global__ __launch_bounds__(256) void convert_f32_bf16(
    const float* __restrict__ in, unsigned short* __restrict__ out) {
    const int idx = (blockIdx.x * 256 + threadIdx.x) * 8;
    float4 v0 = *(const float4*)(in + idx);
    float4 v1 = *(const float4*)(in + idx + 4);
    ushort8v o;
    o[0] = f2bf(v0.x); o[1] = f2bf(v0.y); o[2] = f2bf(v0.z); o[3] = f2bf(v0.w);
    o[4] = f2bf(v1.x); o[5] = f2bf(v1.y); o[6] = f2bf(v1.z); o[7] = f2bf(v1.w);
    *(ushort8v*)(out + idx) = o;  // 16B store
}

// ---------------- fused GEMM: A fp32 staged via DMA, W bf16 ----------------
// A LDS layout: 128 rows x 16 chunks (chunk = 4 fp32 = 16B); global chunk c of
// row r lives at slot c ^ ((r&7)<<1).  Pair-preserving XOR (even<->even) so a
// fragment's 32B (slots 2kc, 2kc+1) stays contiguous.
// B LDS layout: 128 rows x 8 chunks (chunk = 8 bf16 = 16B); slot c ^ (r&7).
// Both staged by global_load_lds with PRE-SWIZZLED global source (linear LDS
// dest in lane order -- the only layout gload_lds supports, m104/m173).
__global__ __launch_bounds__(256, 3) void gemm_fused(
    const float* __restrict__ A,            // [M,K] fp32
    const unsigned short* __restrict__ W,   // [N,K] bf16
    const float* __restrict__ bias,         // [N]
    float* __restrict__ C)                  // [M,N] fp32
{
    __shared__ float          As[BM * BK];  // 32 KB (fp32)
    __shared__ unsigned short Bs[BN * BK];  // 16 KB (bf16)

    const int tid  = threadIdx.x;
    const int wave = tid >> 6;
    const int lane = tid & 63;

    // XCD-aware swizzle: 2048 blocks = 256 M-tiles x 8 N-tiles, 8 XCDs.
    // bid%8 -> XCD; each XCD owns M-tiles [xcd*32, xcd*32+32), n fastest, so the
    // 8 blocks sharing an A-tile are time-adjacent on ONE per-XCD L2.
    const int bid = blockIdx.x;
    const int xcd = bid & 7;
    const int loc = bid >> 3;                      // 0..255
    const int bm0 = (xcd * 32 + (loc >> 3)) * BM;  // bijective over 256 M-tiles
    const int bn0 = (loc & 7) * BN;

    const int wr   = wave >> 1;        // wave row slab (64)
    const int wc   = wave & 1;         // wave col slab (64)
    const int l31  = lane & 31;
    const int half = lane >> 5;        // 0..1

    f32x16 acc[2][2];
#pragma unroll
    for (int i = 0; i < 2; ++i)
#pragma unroll
        for (int j = 0; j < 2; ++j)
#pragma unroll
            for (int r = 0; r < 16; ++r)
                acc[i][j][r] = 0.f;

    const float* Ag          = A + (size_t)bm0 * K_DIM;
    const unsigned short* Wg = W + (size_t)bn0 * K_DIM;

    for (int kt = 0; kt < K_DIM; kt += BK) {
        __syncthreads();  // previous compute's LDS reads done

        // A stage: 8 x global_load_lds dwordx4 (fp32 source, pre-swizzled chunk)
#pragma unroll
        for (int p = 0; p < 8; ++p) {
            const int s     = p * 256 + tid;                 // 16B chunk id
            const int row   = s >> 4;                        // 0..127
            const int c     = (s & 15) ^ ((row & 7) << 1);   // src chunk
            const int goff  = row * K_DIM + kt + c * 4;      // fp32 elems
            const int lbase = (p * 256 + wave * 64) * 4;     // fp32 elems (wave-uniform)
            __builtin_amdgcn_global_load_lds((gptr_t)(Ag + goff), (lptr_t)(As + lbase), 16, 0, 0);
        }
        // B stage: 4 x global_load_lds dwordx4 (bf16 source, pre-swizzled chunk)
#pragma unroll
        for (int p = 0; p < 4; ++p) {
            const int s     = p * 256 + tid;
            const int row   = s >> 3;
            const int c     = (s & 7) ^ (row & 7);
            const int goff  = row * K_DIM + kt + c * 8;      // bf16 elems
            const int lbase = (p * 256 + wave * 64) * 8;     // bf16 elems (wave-uniform)
            __builtin_amdgcn_global_load_lds((gptr_t)(Wg + goff), (lptr_t)(Bs + lbase), 16, 0, 0);
        }

        __syncthreads();  // drains vmcnt(0): both tiles resident

        // Compute: 4 k-steps of K=16, 16 x mfma_f32_32x32x16_bf16.
        // A fragments: 32B fp32 LDS read + in-register cvt (VALU co-schedules
        // with MFMA across the 3 resident blocks -- m114).
#pragma unroll
        for (int ks = 0; ks < 4; ++ks) {
            const int kc = ks * 2 + half;          // 8-elem chunk index 0..7
            bf16x8 af[2], bfv[2];
#pragma unroll
            for (int i = 0; i < 2; ++i) {
                const int arw  = wr * 64 + i * 32 + l31;
                const int slot = (2 * kc) ^ ((arw & 7) << 1);   // 16B slot pair base
                const float4 f0 = *(const float4*)(As + arw * 64 + slot * 4);
                const float4 f1 = *(const float4*)(As + arw * 64 + slot * 4 + 4);
                af[i] = cvt8(f0, f1);
                const int brw = wc * 64 + i * 32 + l31;
                bfv[i] = *(const bf16x8*)(Bs + brw * 64 + (kc ^ (brw & 7)) * 8);
            }
#pragma unroll
            for (int i = 0; i < 2; ++i)
#pragma unroll
                for (int j = 0; j < 2; ++j)
                    acc[i][j] = __builtin_amdgcn_mfma_f32_32x32x16_bf16(
                        af[i], bfv[j], acc[i][j], 0, 0, 0);
        }
    }

    // Epilogue: +bias, fp32 store.
    // C/D 32x32: col = lane&31, row = (reg&3) + 8*(reg>>2) + 4*(lane>>5)  [m74/m101]
#pragma unroll
    for (int j = 0; j < 2; ++j) {
        const int col = bn0 + wc * 64 + j * 32 + l31;
        const float bj = bias[col];
#pragma unroll
        for (int i = 0; i < 2; ++i) {
            const int rbase = bm0 + wr * 64 + i * 32 + 4 * half;
#pragma unroll
            for (int reg = 0; reg < 16; ++reg) {
                const int row = rbase + (reg & 3) + 8 * (reg >> 2);
                C[(size_t)row * N_DIM + col] = acc[i][j][reg] + bj;
            }
        }
    }
}

// ---------------- fallback (fully fused, no workspace) ----------------
#define LDK 40
__global__ __launch_bounds__(256) void groupfc_fused(
    const float* __restrict__ A, const float* __restrict__ W,
    const float* __restrict__ bias, float* __restrict__ C)
{
    __shared__ unsigned short As[BM * LDK];
    __shared__ unsigned short Bs[BN * LDK];
    const int tid = threadIdx.x;
    const int bm0 = blockIdx.x * BM, bn0 = blockIdx.y * BN;
    const int wave = tid >> 6, lane = tid & 63;
    const int wr = wave >> 1, wc = wave & 1;
    const int l15 = lane & 15, quad = lane >> 4;
    typedef __attribute__((ext_vector_type(4))) float f32x4;
    f32x4 acc[4][4];
#pragma unroll
    for (int i = 0; i < 4; ++i)
#pragma unroll
        for (int j = 0; j < 4; ++j) acc[i][j] = (f32x4){0.f, 0.f, 0.f, 0.f};
    const int srow = tid >> 3, sf4 = tid & 7;
    const float* Ag = A + bm0 * K_DIM;
    const float* Wg = W + bn0 * K_DIM;
    for (int kt = 0; kt < K_DIM; kt += 32) {
        __syncthreads();
        float4 av[4], bv[4];
#pragma unroll
        for (int p = 0; p < 4; ++p) {
            const int row = p * 32 + srow;
            av[p] = *(const float4*)(Ag + row * K_DIM + kt + sf4 * 4);
            bv[p] = *(const float4*)(Wg + row * K_DIM + kt + sf4 * 4);
        }
#pragma unroll
        for (int p = 0; p < 4; ++p) {
            const int row = p * 32 + srow;
            ushort4 a16, b16;
            a16.x = f2bf(av[p].x); a16.y = f2bf(av[p].y);
            a16.z = f2bf(av[p].z); a16.w = f2bf(av[p].w);
            b16.x = f2bf(bv[p].x); b16.y = f2bf(bv[p].y);
            b16.z = f2bf(bv[p].z); b16.w = f2bf(bv[p].w);
            *(ushort4*)(&As[row * LDK + sf4 * 4]) = a16;
            *(ushort4*)(&Bs[row * LDK + sf4 * 4]) = b16;
        }
        __syncthreads();
        bf16x8 af[4], bfv[4];
#pragma unroll
        for (int i = 0; i < 4; ++i) {
            af[i]  = *(const bf16x8*)(&As[(wr * 64 + i * 16 + l15) * LDK + quad * 8]);
            bfv[i] = *(const bf16x8*)(&Bs[(wc * 64 + i * 16 + l15) * LDK + quad * 8]);
        }
#pragma unroll
        for (int i = 0; i < 4; ++i)
#pragma unroll
            for (int j = 0; j < 4; ++j)
                acc[i][j] = __builtin_amdgcn_mfma_f32_16x16x32_bf16(af[i], bfv[j], acc[i][j], 0, 0, 0);
    }
#pragma unroll
    for (int j = 0; j < 4; ++j) {
        const int col = bn0 + wc * 64 + j * 16 + l15;
        const float bj = bias[col];
#pragma unroll
        for (int i = 0; i < 4; ++i) {
            const int row0 = bm0 + wr * 64 + i * 16 + quad * 4;
#pragma unroll
            for (int r = 0; r < 4; ++r) C[(row0 + r) * N_DIM + col] = acc[i][j][r] + bj;
        }
    }
}

extern "C" void kernel_launch(void* const* d_in, const int* in_sizes, int n_in,
                              void* d_out, int out_size, void* d_ws, size_t ws_size,
                              hipStream_t stream) {
    const float* A    = (const float*)d_in[0];
    const float* W    = (const float*)d_in[1];
    const float* bias = (const float*)d_in[2];
    float* C          = (float*)d_out;

    const size_t w_elems = (size_t)N_DIM * K_DIM;
    const size_t need    = w_elems * sizeof(unsigned short);  // 2 MB

    if (ws_size >= need) {
        unsigned short* Wbf = (unsigned short*)d_ws;
        convert_f32_bf16<<<dim3(w_elems / (256 * 8)), dim3(256), 0, stream>>>(W, Wbf);
        gemm_fused<<<dim3((M_DIM / BM) * (N_DIM / BN)), dim3(256), 0, stream>>>(A, Wbf, bias, C);
    } else {
        dim3 grid(M_DIM / BM, N_DIM / BN);
        groupfc_fused<<<grid, dim3(256), 0, stream>>>(A, W, bias, C);
    }
}

// Round 3
// 316.474 us; speedup vs baseline: 1.2152x; 1.2152x over previous
//
#include <hip/hip_runtime.h>
#include <hip/hip_bf16.h>

// GroupFC: C[32768,1024] = A[32768,1024] @ W[1024,1024]^T + b[1024], fp32 in/out.
// R6: fused single-pass GEMM, combining the proven pieces of R3/R4 and fixing
// R5's regression:
//   - A LDS tile is bf16 (R3 layout: 128 rows x 8 chunks of 8 bf16, chunk c of
//     row r at slot c^(r&7)) -- 4-way-max bank conflicts (8.4M counter in R3),
//     NOT R5's fp32 tile whose 256B row stride collapsed the XOR swizzle to 4
//     bank positions (8-way conflicts, 86M counter, 233us).
//   - A is reg-staged fp32 -> cvt -> ds_write_b128, with DEPTH-2 ping-pong
//     register buffers: tile t+2's global loads issue right after barrier 2 of
//     tile t, giving ~2 K-iterations of HBM-latency cover (R4's depth-1 gave
//     <1 MFMA phase -> per-iter stall, 150us).  Buffer choice is compile-time
//     (two explicit STEP bodies per loop iter -- runtime-indexed reg arrays
//     spill to scratch).
//   - W bf16 (2 MB pre-convert) via global_load_lds; XCD-aware bijective grid
//     swizzle kept (FETCH 265 -> ~110 MB).

#define M_DIM 32768
#define N_DIM 1024
#define K_DIM 1024
#define BM 128
#define BN 128
#define BK 64

typedef __attribute__((ext_vector_type(8))) short bf16x8;
typedef __attribute__((ext_vector_type(16))) float f32x16;
typedef __attribute__((ext_vector_type(8))) unsigned short ushort8v;

typedef const __attribute__((address_space(1))) unsigned int* gptr_t;
typedef __attribute__((address_space(3))) unsigned int* lptr_t;

static __device__ __forceinline__ unsigned short f2bf(float x) {
    union { __hip_bfloat16 h; unsigned short u; } cv;
    cv.h = __float2bfloat16(x);  // RNE
    return cv.u;
}

static __device__ __forceinline__ ushort8v cvt8(float4 lo, float4 hi) {
    ushort8v r;
    r[0] = f2bf(lo.x); r[1] = f2bf(lo.y); r[2] = f2bf(lo.z); r[3] = f2bf(lo.w);
    r[4] = f2bf(hi.x); r[5] = f2bf(hi.y); r[6] = f2bf(hi.z); r[7] = f2bf(hi.w);
    return r;
}

// ---------------- pass 1 (W only, 2 MB): fp32 -> bf16 ----------------
__global__ __launch_bounds__(256) void convert_f32_bf16(
    const float* __restrict__ in, unsigned short* __restrict__ out) {
    const int idx = (blockIdx.x * 256 + threadIdx.x) * 8;
    float4 v0 = *(const float4*)(in + idx);
    float4 v1 = *(const float4*)(in + idx + 4);
    ushort8v o;
    o[0] = f2bf(v0.x); o[1] = f2bf(v0.y); o[2] = f2bf(v0.z); o[3] = f2bf(v0.w);
    o[4] = f2bf(v1.x); o[5] = f2bf(v1.y); o[6] = f2bf(v1.z); o[7] = f2bf(v1.w);
    *(ushort8v*)(out + idx) = o;  // 16B store
}

// ---------------- fused GEMM: A fp32 reg-staged (depth-2), W bf16 ----------
__global__ __launch_bounds__(256) void gemm_fused(
    const float* __restrict__ A,            // [M,K] fp32
    const unsigned short* __restrict__ W,   // [N,K] bf16
    const float* __restrict__ bias,         // [N]
    float* __restrict__ C)                  // [M,N] fp32
{
    __shared__ unsigned short As[BM * BK];  // 16 KB bf16
    __shared__ unsigned short Bs[BN * BK];  // 16 KB bf16

    const int tid  = threadIdx.x;
    const int wave = tid >> 6;
    const int lane = tid & 63;

    // XCD-aware swizzle: 2048 blocks = 256 M-tiles x 8 N-tiles, 8 XCDs.
    // bid%8 -> XCD; each XCD owns M-tiles [xcd*32, xcd*32+32), n fastest, so the
    // 8 blocks sharing an A-tile are time-adjacent on ONE per-XCD L2.
    const int bid = blockIdx.x;
    const int xcd = bid & 7;
    const int loc = bid >> 3;                      // 0..255
    const int bm0 = (xcd * 32 + (loc >> 3)) * BM;  // bijective over 256 M-tiles
    const int bn0 = (loc & 7) * BN;

    const int wr   = wave >> 1;        // wave row slab (64)
    const int wc   = wave & 1;         // wave col slab (64)
    const int l31  = lane & 31;
    const int half = lane >> 5;        // 0..1

    f32x16 acc[2][2];
#pragma unroll
    for (int i = 0; i < 2; ++i)
#pragma unroll
        for (int j = 0; j < 2; ++j)
#pragma unroll
            for (int r = 0; r < 16; ++r)
                acc[i][j][r] = 0.f;

    const float* Ag          = A + (size_t)bm0 * K_DIM;
    const unsigned short* Wg = W + (size_t)bn0 * K_DIM;

    // Per-thread A staging descriptors: 4 chunks of 8 fp32 (=8 bf16 out) each.
    int aoff[4];   // element offset within tile-row space (add kt at use)
    int lslot[4];  // LDS slot (16B units) for the swizzled bf16 write
#pragma unroll
    for (int p = 0; p < 4; ++p) {
        const int s   = p * 256 + tid;
        const int row = s >> 3;                       // 0..127
        const int cn  = s & 7;                        // chunk col 0..7
        aoff[p]  = row * K_DIM + cn * 8;
        lslot[p] = row * 8 + (cn ^ (row & 7));
    }

    float4 bufA[4][2], bufB[4][2];  // depth-2 ping-pong A staging (32+32 VGPR)

    auto LOADA = [&](float4 (&buf)[4][2], int kt) {
#pragma unroll
        for (int p = 0; p < 4; ++p) {
            const float* src = Ag + aoff[p] + kt;
            buf[p][0] = *(const float4*)(src);
            buf[p][1] = *(const float4*)(src + 4);
        }
    };

    // STEP: process K-tile ktp (A data already in buf), refill buf from ktn.
    auto STEP = [&](float4 (&buf)[4][2], int ktp, int ktn) {
        __syncthreads();  // previous compute's LDS reads done

        // B stage: 4 x global_load_lds dwordx4 (bf16 src, pre-swizzled chunk)
#pragma unroll
        for (int p = 0; p < 4; ++p) {
            const int s     = p * 256 + wave * 64 + lane;
            const int row   = s >> 3;
            const int c     = (s & 7) ^ (row & 7);
            const int goff  = row * K_DIM + ktp + c * 8;   // bf16 elems
            const int lbase = (p * 256 + wave * 64) * 8;   // wave-uniform
            __builtin_amdgcn_global_load_lds((gptr_t)(Wg + goff), (lptr_t)(Bs + lbase), 16, 0, 0);
        }

        // A stage: cvt reg-buffer -> bf16, swizzled ds_write_b128
#pragma unroll
        for (int p = 0; p < 4; ++p)
            *(ushort8v*)(As + lslot[p] * 8) = cvt8(buf[p][0], buf[p][1]);

        __syncthreads();  // drains vmcnt (B resident) + lgkm (A writes visible)

        // Refill buf with tile ktn NOW: ~2 full K-iterations before consumption
        // at tile ktn's cvt phase -> HBM latency fully covered.
        if (ktn < K_DIM) LOADA(buf, ktn);

        // Compute: 4 k-steps of K=16, 16 x mfma_f32_32x32x16_bf16
#pragma unroll
        for (int ks = 0; ks < 4; ++ks) {
            const int kc = ks * 2 + half;          // 8-elem chunk index
            bf16x8 af[2], bfv[2];
#pragma unroll
            for (int i = 0; i < 2; ++i) {
                const int arw = wr * 64 + i * 32 + l31;
                af[i]  = *(const bf16x8*)(As + arw * 64 + (kc ^ (arw & 7)) * 8);
                const int brw = wc * 64 + i * 32 + l31;
                bfv[i] = *(const bf16x8*)(Bs + brw * 64 + (kc ^ (brw & 7)) * 8);
            }
#pragma unroll
            for (int i = 0; i < 2; ++i)
#pragma unroll
                for (int j = 0; j < 2; ++j)
                    acc[i][j] = __builtin_amdgcn_mfma_f32_32x32x16_bf16(
                        af[i], bfv[j], acc[i][j], 0, 0, 0);
        }
    };

    // Prologue: tiles 0 and 1 into the two buffers.
    LOADA(bufA, 0);
    LOADA(bufB, BK);

    // 16 K-tiles, two per loop iteration (compile-time buffer binding).
    for (int kt = 0; kt < K_DIM; kt += 2 * BK) {
        STEP(bufA, kt, kt + 2 * BK);
        STEP(bufB, kt + BK, kt + 3 * BK);
    }

    // Epilogue: +bias, fp32 store.
    // C/D 32x32: col = lane&31, row = (reg&3) + 8*(reg>>2) + 4*(lane>>5)  [m74/m101]
#pragma unroll
    for (int j = 0; j < 2; ++j) {
        const int col = bn0 + wc * 64 + j * 32 + l31;
        const float bj = bias[col];
#pragma unroll
        for (int i = 0; i < 2; ++i) {
            const int rbase = bm0 + wr * 64 + i * 32 + 4 * half;
#pragma unroll
            for (int reg = 0; reg < 16; ++reg) {
                const int row = rbase + (reg & 3) + 8 * (reg >> 2);
                C[(size_t)row * N_DIM + col] = acc[i][j][reg] + bj;
            }
        }
    }
}

// ---------------- fallback (fully fused, no workspace) ----------------
#define LDK 40
__global__ __launch_bounds__(256) void groupfc_fused(
    const float* __restrict__ A, const float* __restrict__ W,
    const float* __restrict__ bias, float* __restrict__ C)
{
    __shared__ unsigned short As[BM * LDK];
    __shared__ unsigned short Bs[BN * LDK];
    const int tid = threadIdx.x;
    const int bm0 = blockIdx.x * BM, bn0 = blockIdx.y * BN;
    const int wave = tid >> 6, lane = tid & 63;
    const int wr = wave >> 1, wc = wave & 1;
    const int l15 = lane & 15, quad = lane >> 4;
    typedef __attribute__((ext_vector_type(4))) float f32x4;
    f32x4 acc[4][4];
#pragma unroll
    for (int i = 0; i < 4; ++i)
#pragma unroll
        for (int j = 0; j < 4; ++j) acc[i][j] = (f32x4){0.f, 0.f, 0.f, 0.f};
    const int srow = tid >> 3, sf4 = tid & 7;
    const float* Ag = A + bm0 * K_DIM;
    const float* Wg = W + bn0 * K_DIM;
    for (int kt = 0; kt < K_DIM; kt += 32) {
        __syncthreads();
        float4 av[4], bv[4];
#pragma unroll
        for (int p = 0; p < 4; ++p) {
            const int row = p * 32 + srow;
            av[p] = *(const float4*)(Ag + row * K_DIM + kt + sf4 * 4);
            bv[p] = *(const float4*)(Wg + row * K_DIM + kt + sf4 * 4);
        }
#pragma unroll
        for (int p = 0; p < 4; ++p) {
            const int row = p * 32 + srow;
            ushort4 a16, b16;
            a16.x = f2bf(av[p].x); a16.y = f2bf(av[p].y);
            a16.z = f2bf(av[p].z); a16.w = f2bf(av[p].w);
            b16.x = f2bf(bv[p].x); b16.y = f2bf(bv[p].y);
            b16.z = f2bf(bv[p].z); b16.w = f2bf(bv[p].w);
            *(ushort4*)(&As[row * LDK + sf4 * 4]) = a16;
            *(ushort4*)(&Bs[row * LDK + sf4 * 4]) = b16;
        }
        __syncthreads();
        bf16x8 af[4], bfv[4];
#pragma unroll
        for (int i = 0; i < 4; ++i) {
            af[i]  = *(const bf16x8*)(&As[(wr * 64 + i * 16 + l15) * LDK + quad * 8]);
            bfv[i] = *(const bf16x8*)(&Bs[(wc * 64 + i * 16 + l15) * LDK + quad * 8]);
        }
#pragma unroll
        for (int i = 0; i < 4; ++i)
#pragma unroll
            for (int j = 0; j < 4; ++j)
                acc[i][j] = __builtin_amdgcn_mfma_f32_16x16x32_bf16(af[i], bfv[j], acc[i][j], 0, 0, 0);
    }
#pragma unroll
    for (int j = 0; j < 4; ++j) {
        const int col = bn0 + wc * 64 + j * 16 + l15;
        const float bj = bias[col];
#pragma unroll
        for (int i = 0; i < 4; ++i) {
            const int row0 = bm0 + wr * 64 + i * 16 + quad * 4;
#pragma unroll
            for (int r = 0; r < 4; ++r) C[(row0 + r) * N_DIM + col] = acc[i][j][r] + bj;
        }
    }
}

extern "C" void kernel_launch(void* const* d_in, const int* in_sizes, int n_in,
                              void* d_out, int out_size, void* d_ws, size_t ws_size,
                              hipStream_t stream) {
    const float* A    = (const float*)d_in[0];
    const float* W    = (const float*)d_in[1];
    const float* bias = (const float*)d_in[2];
    float* C          = (float*)d_out;

    const size_t w_elems = (size_t)N_DIM * K_DIM;
    const size_t need    = w_elems * sizeof(unsigned short);  // 2 MB

    if (ws_size >= need) {
        unsigned short* Wbf = (unsigned short*)d_ws;
        convert_f32_bf16<<<dim3(w_elems / (256 * 8)), dim3(256), 0, stream>>>(W, Wbf);
        gemm_fused<<<dim3((M_DIM / BM) * (N_DIM / BN)), dim3(256), 0, stream>>>(A, Wbf, bias, C);
    } else {
        dim3 grid(M_DIM / BM, N_DIM / BN);
        groupfc_fused<<<grid, dim3(256), 0, stream>>>(A, W, bias, C);
    }
}